// Round 4
// baseline (366.388 us; speedup 1.0000x reference)
//
#include <hip/hip_runtime.h>
#include <hip/hip_bf16.h>
#include <math.h>

#define S_LEN 2048
#define DMODEL 2048
#define NH 16
#define NKVH 4
#define HDIM 128
#define WINDOW 1024

typedef __bf16 bf16;
typedef __bf16 bf16x8 __attribute__((ext_vector_type(8)));
typedef float floatx4 __attribute__((ext_vector_type(4)));

static __device__ __forceinline__ bf16x8 load_bf8(const bf16* p) {
    return *reinterpret_cast<const bf16x8*>(p);
}

// async 16B global->LDS (wave-uniform LDS base + lane*16)
static __device__ __forceinline__ void async16(const bf16* g, bf16* l) {
    __builtin_amdgcn_global_load_lds(
        (const __attribute__((address_space(1))) void*)g,
        (__attribute__((address_space(3))) void*)l, 16, 0, 0);
}

// ---------------- fp32 -> bf16 conversion of x and all weights ----------------
__global__ __launch_bounds__(256) void convert_kernel(
    const float* __restrict__ x, const float* __restrict__ wq,
    const float* __restrict__ wk, const float* __restrict__ wv,
    const float* __restrict__ wo,
    bf16* __restrict__ xb, bf16* __restrict__ wqb, bf16* __restrict__ wkb,
    bf16* __restrict__ wvb, bf16* __restrict__ wob) {
    int i = blockIdx.x * blockDim.x + threadIdx.x;  // one float4 per thread
    const float* src; bf16* dst; int off;
    if      (i < 1048576) { src = x;  dst = xb;  off = i; }
    else if (i < 2097152) { src = wq; dst = wqb; off = i - 1048576; }
    else if (i < 2359296) { src = wk; dst = wkb; off = i - 2097152; }
    else if (i < 2621440) { src = wv; dst = wvb; off = i - 2359296; }
    else if (i < 3670016) { src = wo; dst = wob; off = i - 2621440; }
    else return;
    float4 v = reinterpret_cast<const float4*>(src)[off];
    union { bf16 b[4]; ushort4 u; } t;
    t.b[0] = (bf16)v.x; t.b[1] = (bf16)v.y; t.b[2] = (bf16)v.z; t.b[3] = (bf16)v.w;
    reinterpret_cast<ushort4*>(dst)[off] = t.u;
}

// ---------------- 128x128-tile GEMM: C = A @ B^T (m97 structure) -------------
// A: [M][K] bf16, B: [N][K] bf16, C: [M][N] OutT. K multiple of 32,
// M,N multiples of 128. 256 threads = 4 waves, each wave computes 64x64.
template <bool CLIP, typename OutT>
__global__ __launch_bounds__(256) void gemm128(
    const bf16* __restrict__ A, const bf16* __restrict__ B,
    OutT* __restrict__ C, int N, int K) {
    __shared__ __align__(16) bf16 sA[128 * 32];  // 8 KB, row-major [128][32]
    __shared__ __align__(16) bf16 sB[128 * 32];  // 8 KB
    int tid = threadIdx.x;
    int lane = tid & 63, wid = tid >> 6;
    int l15 = lane & 15, quad = lane >> 4;
    int m0 = blockIdx.y * 128, n0 = blockIdx.x * 128;

    // staging: thread covers (row = wid*16 + lane/4 [+64], col = (lane&3)*8)
    int srow = wid * 16 + (lane >> 2);
    int scol = (lane & 3) * 8;
    const bf16* gA0 = A + (size_t)(m0 + srow) * K + scol;
    const bf16* gA1 = gA0 + (size_t)64 * K;
    const bf16* gB0 = B + (size_t)(n0 + srow) * K + scol;
    const bf16* gB1 = gB0 + (size_t)64 * K;
    bf16* lA0 = sA + (wid * 16) * 32;        // wave-uniform bases
    bf16* lA1 = sA + (64 + wid * 16) * 32;
    bf16* lB0 = sB + (wid * 16) * 32;
    bf16* lB1 = sB + (64 + wid * 16) * 32;

    floatx4 acc[4][4];
#pragma unroll
    for (int mi = 0; mi < 4; ++mi)
#pragma unroll
        for (int ni = 0; ni < 4; ++ni) acc[mi][ni] = floatx4{0.f, 0.f, 0.f, 0.f};

    int mb = (wid & 1) * 64, nb = (wid >> 1) * 64;

    for (int k0 = 0; k0 < K; k0 += 32) {
        async16(gA0 + k0, lA0);
        async16(gA1 + k0, lA1);
        async16(gB0 + k0, lB0);
        async16(gB1 + k0, lB1);
        __syncthreads();   // drains vmcnt (global_load_lds) + orders LDS
        bf16x8 af[4], bq[4];
#pragma unroll
        for (int i = 0; i < 4; ++i) {
            af[i] = load_bf8(sA + (mb + i * 16 + l15) * 32 + quad * 8);
            bq[i] = load_bf8(sB + (nb + i * 16 + l15) * 32 + quad * 8);
        }
#pragma unroll
        for (int mi = 0; mi < 4; ++mi)
#pragma unroll
            for (int ni = 0; ni < 4; ++ni)
                acc[mi][ni] = __builtin_amdgcn_mfma_f32_16x16x32_bf16(
                    af[mi], bq[ni], acc[mi][ni], 0, 0, 0);
        __syncthreads();   // all waves done reading before next stage
    }

#pragma unroll
    for (int mi = 0; mi < 4; ++mi)
#pragma unroll
        for (int ni = 0; ni < 4; ++ni)
#pragma unroll
            for (int r = 0; r < 4; ++r) {
                int m = m0 + mb + mi * 16 + quad * 4 + r;
                int n = n0 + nb + ni * 16 + l15;
                float v = acc[mi][ni][r];
                if (CLIP) v = fminf(fmaxf(v, -8.0f), 8.0f);
                C[(size_t)m * N + n] = (OutT)v;
            }
}

// ---------------- per-head RMSNorm + RoPE; V transposed copy -----------------
__global__ __launch_bounds__(128) void norm_rope(
    const bf16* __restrict__ qkv, const float* __restrict__ qw,
    const float* __restrict__ kw, bf16* __restrict__ qb,
    bf16* __restrict__ kb, bf16* __restrict__ vtb) {
    int s = blockIdx.x;
    int idx = blockIdx.y;      // 0..15 = q heads, 16..19 = k heads (+v copy)
    int d = threadIdx.x;       // 0..127
    bool isq = idx < 16;
    int off = isq ? idx * 128 : 2048 + (idx - 16) * 128;
    float val = (float)qkv[(size_t)s * 3072 + off + d];

    float ss = val * val;
#pragma unroll
    for (int o = 32; o > 0; o >>= 1) ss += __shfl_xor(ss, o, 64);
    __shared__ float wsum[2];
    __shared__ float xs[128];
    if ((threadIdx.x & 63) == 0) wsum[threadIdx.x >> 6] = ss;
    __syncthreads();
    float var = (wsum[0] + wsum[1]) * (1.0f / 128.0f);
    float nw = isq ? qw[d] : kw[d];
    float xn = val * rsqrtf(var + 1e-6f) * nw;
    xs[d] = xn;
    __syncthreads();
    float part = xs[d ^ 64];
    float rot = (d < 64) ? -part : part;
    int fi = d & 63;
    // inv_freq = theta^(-fi/64); ln(500000) = 13.122363377404328
    float inv = expf((float)fi * (-13.122363377404328f / 64.0f));
    float ang = (float)s * inv;
    float c = cosf(ang), sn = sinf(ang);
    float outv = xn * c + rot * sn;
    if (isq) {
        qb[(size_t)s * 2048 + idx * 128 + d] = (bf16)outv;
    } else {
        int kh = idx - 16;
        kb[(size_t)s * 512 + kh * 128 + d] = (bf16)outv;
        bf16 vv = qkv[(size_t)s * 3072 + 2560 + kh * 128 + d];
        vtb[((size_t)(kh * 128 + d)) * 2048 + s] = vv;  // V^T: [kvh*128+d][s]
    }
}

// ---------------- flash attention, sliding window + sink ---------------------
// No online max: |logit| <= sqrt(128) ~ 11.3 (RMS-normed q,k), so exp() with
// fixed m=0 stays in fp32 range (l <= 1024*e^11.3 ~ 8e7). One end reduction.
__global__ __launch_bounds__(256) void attn(
    const bf16* __restrict__ qb, const bf16* __restrict__ kb,
    const bf16* __restrict__ vtb, const float* __restrict__ sinks,
    bf16* __restrict__ attb) {
    int lane = threadIdx.x & 63;
    int wid  = threadIdx.x >> 6;
    int h = blockIdx.y;
    int kh = h >> 2;
    int qw0 = blockIdx.x * 64 + wid * 16;
    int l15 = lane & 15, quad = lane >> 4;

    __shared__ __align__(16) bf16 ldsp[4][16 * 64];  // 8 KB: per-wave P tile
    bf16* myp = ldsp[wid];

    // Q fragments: A[m=l15][k=quad*8+j], 4 chunks of k=32 covering HD=128
    bf16x8 qf[4];
    const bf16* qrow = qb + (size_t)(qw0 + l15) * 2048 + h * 128 + quad * 8;
#pragma unroll
    for (int kc = 0; kc < 4; ++kc) qf[kc] = load_bf8(qrow + kc * 32);

    floatx4 acc[8];
#pragma unroll
    for (int f = 0; f < 8; ++f) acc[f] = floatx4{0.f, 0.f, 0.f, 0.f};
    float lpart[4] = {0.f, 0.f, 0.f, 0.f};

    int qi_base = qw0 + quad * 4;
    int start = qw0 - (WINDOW - 1); if (start < 0) start = 0;
    int t0 = start & ~63;

    for (int t = t0; t <= qw0 + 15; t += 64) {
        floatx4 s[4];
#pragma unroll
        for (int c = 0; c < 4; ++c) s[c] = floatx4{0.f, 0.f, 0.f, 0.f};
        const bf16* kr = kb + (size_t)(t + l15) * 512 + kh * 128 + quad * 8;
#pragma unroll
        for (int c = 0; c < 4; ++c)
#pragma unroll
            for (int kc = 0; kc < 4; ++kc) {
                bf16x8 b = load_bf8(kr + (size_t)c * 16 * 512 + kc * 32);
                s[c] = __builtin_amdgcn_mfma_f32_16x16x32_bf16(qf[kc], b, s[c], 0, 0, 0);
            }
        // scale+mask+exp, accumulate row partial sums, stash P to LDS
#pragma unroll
        for (int r = 0; r < 4; ++r) {
            int qi = qi_base + r;
            int row = (quad * 4 + r) * 64;
#pragma unroll
            for (int c = 0; c < 4; ++c) {
                int ki = t + c * 16 + l15;
                float v = s[c][r] * 0.08838834764831845f;  // 1/sqrt(128)
                bool ok = (ki <= qi) && (ki > qi - WINDOW);
                float e = ok ? __expf(v) : 0.0f;
                lpart[r] += e;
                myp[row + c * 16 + l15] = (bf16)e;
            }
        }
        // P (C-layout rows) -> A-layout fragments (same wave, DS in-order)
        bf16x8 pa0 = load_bf8(myp + l15 * 64 + quad * 8);
        bf16x8 pa1 = load_bf8(myp + l15 * 64 + 32 + quad * 8);
        const bf16* vcol = vtb + ((size_t)(kh * 128 + l15)) * 2048 + t + quad * 8;
#pragma unroll
        for (int f = 0; f < 8; ++f) {
            bf16x8 vb0 = load_bf8(vcol + (size_t)f * 16 * 2048);
            bf16x8 vb1 = load_bf8(vcol + (size_t)f * 16 * 2048 + 32);
            acc[f] = __builtin_amdgcn_mfma_f32_16x16x32_bf16(pa0, vb0, acc[f], 0, 0, 0);
            acc[f] = __builtin_amdgcn_mfma_f32_16x16x32_bf16(pa1, vb1, acc[f], 0, 0, 0);
        }
    }

    // one shuffle reduction at the end; fold sink; normalize; store
    float sk = __expf(sinks[h]);
#pragma unroll
    for (int r = 0; r < 4; ++r) {
        float rs = lpart[r];
#pragma unroll
        for (int o = 1; o < 16; o <<= 1) rs += __shfl_xor(rs, o, 64);
        float inv = 1.0f / (rs + sk);
        int m = qw0 + quad * 4 + r;
#pragma unroll
        for (int f = 0; f < 8; ++f) {
            attb[(size_t)m * 2048 + h * 128 + f * 16 + l15] = (bf16)(acc[f][r] * inv);
        }
    }
}

extern "C" void kernel_launch(void* const* d_in, const int* in_sizes, int n_in,
                              void* d_out, int out_size, void* d_ws, size_t ws_size,
                              hipStream_t stream) {
    const float* x      = (const float*)d_in[0];
    const float* w_q    = (const float*)d_in[1];
    const float* w_k    = (const float*)d_in[2];
    const float* w_v    = (const float*)d_in[3];
    const float* w_out  = (const float*)d_in[4];
    const float* q_norm = (const float*)d_in[5];
    const float* k_norm = (const float*)d_in[6];
    const float* sinks  = (const float*)d_in[7];

    char* ws = (char*)d_ws;
    const size_t MB = 1u << 20;
    bf16* xb   = (bf16*)(ws + 0 * MB);    // 8 MB
    bf16* wqb  = (bf16*)(ws + 8 * MB);    // 8 MB  (wqb/wkb/wvb contiguous)
    bf16* wkb  = (bf16*)(ws + 16 * MB);   // 2 MB  (forms wcomb [3072][2048])
    bf16* wvb  = (bf16*)(ws + 18 * MB);   // 2 MB
    bf16* wob  = (bf16*)(ws + 20 * MB);   // 8 MB
    bf16* qkv  = (bf16*)(ws + 28 * MB);   // 12 MB (S x 3072, post-clip)
    bf16* qb   = (bf16*)(ws + 40 * MB);   // 8 MB  (post norm+rope)
    bf16* kb   = (bf16*)(ws + 48 * MB);   // 2 MB
    bf16* vtb  = (bf16*)(ws + 50 * MB);   // 2 MB  (V transposed)
    bf16* attb = (bf16*)(ws + 52 * MB);   // 8 MB
    bf16* wcomb = wqb;                    // rows 0..3071 = [w_q; w_k; w_v]
    float* out = (float*)d_out;

    convert_kernel<<<14336, 256, 0, stream>>>(x, w_q, w_k, w_v, w_out,
                                              xb, wqb, wkb, wvb, wob);
    gemm128<true, bf16><<<dim3(24, 16), 256, 0, stream>>>(xb, wcomb, qkv, 3072, 2048);
    norm_rope<<<dim3(2048, 20), 128, 0, stream>>>(qkv, q_norm, k_norm, qb, kb, vtb);
    attn<<<dim3(32, 16), 256, 0, stream>>>(qb, kb, vtb, sinks, attb);
    gemm128<false, float><<<dim3(16, 16), 256, 0, stream>>>(attb, wob, out, 2048, 2048);
}

// Round 5
// 259.180 us; speedup vs baseline: 1.4136x; 1.4136x over previous
//
#include <hip/hip_runtime.h>
#include <hip/hip_bf16.h>
#include <math.h>

#define S_LEN 2048
#define DMODEL 2048
#define NH 16
#define NKVH 4
#define HDIM 128
#define WINDOW 1024

typedef __bf16 bf16;
typedef __bf16 bf16x8 __attribute__((ext_vector_type(8)));
typedef float floatx4 __attribute__((ext_vector_type(4)));

static __device__ __forceinline__ bf16x8 load_bf8(const bf16* p) {
    return *reinterpret_cast<const bf16x8*>(p);
}

// async 16B global->LDS (wave-uniform LDS base + lane*16)
static __device__ __forceinline__ void async16(const bf16* g, bf16* l) {
    __builtin_amdgcn_global_load_lds(
        (const __attribute__((address_space(1))) void*)g,
        (__attribute__((address_space(3))) void*)l, 16, 0, 0);
}

// ---------------- fp32 -> bf16 conversion of x and all weights ----------------
__global__ __launch_bounds__(256) void convert_kernel(
    const float* __restrict__ x, const float* __restrict__ wq,
    const float* __restrict__ wk, const float* __restrict__ wv,
    const float* __restrict__ wo,
    bf16* __restrict__ xb, bf16* __restrict__ wqb, bf16* __restrict__ wkb,
    bf16* __restrict__ wvb, bf16* __restrict__ wob) {
    int i = blockIdx.x * blockDim.x + threadIdx.x;  // one float4 per thread
    const float* src; bf16* dst; int off;
    if      (i < 1048576) { src = x;  dst = xb;  off = i; }
    else if (i < 2097152) { src = wq; dst = wqb; off = i - 1048576; }
    else if (i < 2359296) { src = wk; dst = wkb; off = i - 2097152; }
    else if (i < 2621440) { src = wv; dst = wvb; off = i - 2359296; }
    else if (i < 3670016) { src = wo; dst = wob; off = i - 2621440; }
    else return;
    float4 v = reinterpret_cast<const float4*>(src)[off];
    union { bf16 b[4]; ushort4 u; } t;
    t.b[0] = (bf16)v.x; t.b[1] = (bf16)v.y; t.b[2] = (bf16)v.z; t.b[3] = (bf16)v.w;
    reinterpret_cast<ushort4*>(dst)[off] = t.u;
}

// ---------------- 128x128-tile GEMM: C = A @ B^T (m97 structure) -------------
template <bool CLIP, typename OutT>
__global__ __launch_bounds__(256) void gemm128(
    const bf16* __restrict__ A, const bf16* __restrict__ B,
    OutT* __restrict__ C, int N, int K) {
    __shared__ __align__(16) bf16 sA[128 * 32];  // 8 KB, row-major [128][32]
    __shared__ __align__(16) bf16 sB[128 * 32];  // 8 KB
    int tid = threadIdx.x;
    int lane = tid & 63, wid = tid >> 6;
    int l15 = lane & 15, quad = lane >> 4;
    int m0 = blockIdx.y * 128, n0 = blockIdx.x * 128;

    int srow = wid * 16 + (lane >> 2);
    int scol = (lane & 3) * 8;
    const bf16* gA0 = A + (size_t)(m0 + srow) * K + scol;
    const bf16* gA1 = gA0 + (size_t)64 * K;
    const bf16* gB0 = B + (size_t)(n0 + srow) * K + scol;
    const bf16* gB1 = gB0 + (size_t)64 * K;
    bf16* lA0 = sA + (wid * 16) * 32;        // wave-uniform bases
    bf16* lA1 = sA + (64 + wid * 16) * 32;
    bf16* lB0 = sB + (wid * 16) * 32;
    bf16* lB1 = sB + (64 + wid * 16) * 32;

    floatx4 acc[4][4];
#pragma unroll
    for (int mi = 0; mi < 4; ++mi)
#pragma unroll
        for (int ni = 0; ni < 4; ++ni) acc[mi][ni] = floatx4{0.f, 0.f, 0.f, 0.f};

    int mb = (wid & 1) * 64, nb = (wid >> 1) * 64;

    for (int k0 = 0; k0 < K; k0 += 32) {
        async16(gA0 + k0, lA0);
        async16(gA1 + k0, lA1);
        async16(gB0 + k0, lB0);
        async16(gB1 + k0, lB1);
        __syncthreads();
        bf16x8 af[4], bq[4];
#pragma unroll
        for (int i = 0; i < 4; ++i) {
            af[i] = load_bf8(sA + (mb + i * 16 + l15) * 32 + quad * 8);
            bq[i] = load_bf8(sB + (nb + i * 16 + l15) * 32 + quad * 8);
        }
#pragma unroll
        for (int mi = 0; mi < 4; ++mi)
#pragma unroll
            for (int ni = 0; ni < 4; ++ni)
                acc[mi][ni] = __builtin_amdgcn_mfma_f32_16x16x32_bf16(
                    af[mi], bq[ni], acc[mi][ni], 0, 0, 0);
        __syncthreads();
    }

#pragma unroll
    for (int mi = 0; mi < 4; ++mi)
#pragma unroll
        for (int ni = 0; ni < 4; ++ni)
#pragma unroll
            for (int r = 0; r < 4; ++r) {
                int m = m0 + mb + mi * 16 + quad * 4 + r;
                int n = n0 + nb + ni * 16 + l15;
                float v = acc[mi][ni][r];
                if (CLIP) v = fminf(fmaxf(v, -8.0f), 8.0f);
                C[(size_t)m * N + n] = (OutT)v;
            }
}

// ---------------- per-head RMSNorm + RoPE; V transposed copy -----------------
__global__ __launch_bounds__(128) void norm_rope(
    const bf16* __restrict__ qkv, const float* __restrict__ qw,
    const float* __restrict__ kw, bf16* __restrict__ qb,
    bf16* __restrict__ kb, bf16* __restrict__ vtb) {
    int s = blockIdx.x;
    int idx = blockIdx.y;      // 0..15 = q heads, 16..19 = k heads (+v copy)
    int d = threadIdx.x;       // 0..127
    bool isq = idx < 16;
    int off = isq ? idx * 128 : 2048 + (idx - 16) * 128;
    float val = (float)qkv[(size_t)s * 3072 + off + d];

    float ss = val * val;
#pragma unroll
    for (int o = 32; o > 0; o >>= 1) ss += __shfl_xor(ss, o, 64);
    __shared__ float wsum[2];
    __shared__ float xs[128];
    if ((threadIdx.x & 63) == 0) wsum[threadIdx.x >> 6] = ss;
    __syncthreads();
    float var = (wsum[0] + wsum[1]) * (1.0f / 128.0f);
    float nw = isq ? qw[d] : kw[d];
    float xn = val * rsqrtf(var + 1e-6f) * nw;
    xs[d] = xn;
    __syncthreads();
    float part = xs[d ^ 64];
    float rot = (d < 64) ? -part : part;
    int fi = d & 63;
    // inv_freq = theta^(-fi/64); ln(500000) = 13.122363377404328
    float inv = __expf((float)fi * (-13.122363377404328f / 64.0f));
    float ang = (float)s * inv;
    float c = __cosf(ang), sn = __sinf(ang);
    float outv = xn * c + rot * sn;
    if (isq) {
        qb[(size_t)s * 2048 + idx * 128 + d] = (bf16)outv;
    } else {
        int kh = idx - 16;
        kb[(size_t)s * 512 + kh * 128 + d] = (bf16)outv;
        bf16 vv = qkv[(size_t)s * 3072 + 2560 + kh * 128 + d];
        vtb[((size_t)(kh * 128 + d)) * 2048 + s] = vv;  // V^T: [kvh*128+d][s]
    }
}

// ---------------- flash attention: LDS-staged K/V (m97-style pipeline) -------
// Fixed m=0 softmax (|logit| <= sqrt(128), RMS-normed q,k): partial sums are
// linear, one reduction at end. K/V tiles staged via global_load_lds and
// shared by all 4 waves; chunk index XOR-swizzled to spread LDS banks.
__global__ __launch_bounds__(256) void attn(
    const bf16* __restrict__ qb, const bf16* __restrict__ kb,
    const bf16* __restrict__ vtb, const float* __restrict__ sinks,
    bf16* __restrict__ attb) {
    __shared__ __align__(16) bf16 sK[64 * 128];    // [key][dim], swizzled, 16 KB
    __shared__ __align__(16) bf16 sV[128 * 64];    // [dim][key], swizzled, 16 KB
    __shared__ __align__(16) bf16 sP[4][16 * 72];  // per-wave P, padded stride
    int tid = threadIdx.x;
    int lane = tid & 63, wid = tid >> 6;
    int l15 = lane & 15, quad = lane >> 4;
    int h = blockIdx.y, kh = h >> 2;
    int bq0 = blockIdx.x * 64;
    int qw0 = bq0 + wid * 16;
    bf16* myp = sP[wid];

    // Q fragments: A[m=l15][k=quad*8+j], 4 chunks of k=32 covering HD=128
    bf16x8 qf[4];
    const bf16* qrow = qb + (size_t)(qw0 + l15) * 2048 + h * 128 + quad * 8;
#pragma unroll
    for (int kc = 0; kc < 4; ++kc) qf[kc] = load_bf8(qrow + kc * 32);

    floatx4 acc[8];
#pragma unroll
    for (int f = 0; f < 8; ++f) acc[f] = floatx4{0.f, 0.f, 0.f, 0.f};
    float lpart[4] = {0.f, 0.f, 0.f, 0.f};
    int qi_base = qw0 + quad * 4;

    // staging source columns (XOR chunk swizzle; LDS dest forced = lane*16)
    int keyit = wid * 4 + (lane >> 4);              // key-in-tile mod 16
    int gcK = (lane & 15) ^ keyit;                  // K: 16-chunk rows
    int dimit = wid * 8 + (lane >> 3);              // dim-in-round (0..31)
    int gcV = (lane & 7) ^ ((lane >> 3) & 7);       // V: 8-chunk rows

    int tstart = bq0 - 1024; if (tstart < 0) tstart = 0;
    const bf16* kbase = kb + (size_t)kh * 128;
    const bf16* vbase = vtb + (size_t)kh * 128 * 2048;

    for (int t = tstart; t <= bq0; t += 64) {
        // ---- stage K tile [64][128] and V^T tile [128][64] ----
#pragma unroll
        for (int r = 0; r < 4; ++r) {
            int key = r * 16 + keyit;
            async16(kbase + (size_t)(t + key) * 512 + gcK * 8,
                    sK + (r * 16 + wid * 4) * 128);
            int dim = r * 32 + dimit;
            async16(vbase + (size_t)dim * 2048 + t + gcV * 8,
                    sV + (r * 32 + wid * 8) * 64);
        }
        __syncthreads();   // drains async16 + orders LDS
        bool active = !((t + 63 <= qw0 - WINDOW) || (t > qw0 + 15));
        if (active) {
            // ---- QK^T: 4 key groups x 4 k-chunks ----
            floatx4 s[4];
#pragma unroll
            for (int g = 0; g < 4; ++g) s[g] = floatx4{0.f, 0.f, 0.f, 0.f};
#pragma unroll
            for (int g = 0; g < 4; ++g) {
                int key = g * 16 + l15;
#pragma unroll
                for (int kc = 0; kc < 4; ++kc) {
                    int ch = (kc * 4 + quad) ^ l15;  // unswizzle
                    bf16x8 b = load_bf8(sK + key * 128 + ch * 8);
                    s[g] = __builtin_amdgcn_mfma_f32_16x16x32_bf16(qf[kc], b, s[g], 0, 0, 0);
                }
            }
            // ---- scale+mask+exp -> P (padded LDS), partial row sums ----
#pragma unroll
            for (int r = 0; r < 4; ++r) {
                int qi = qi_base + r;
                int row = (quad * 4 + r) * 72;
#pragma unroll
                for (int g = 0; g < 4; ++g) {
                    int ki = t + g * 16 + l15;
                    float v = s[g][r] * 0.08838834764831845f;  // 1/sqrt(128)
                    bool ok = (ki <= qi) && (ki > qi - WINDOW);
                    float e = ok ? __expf(v) : 0.0f;
                    lpart[r] += e;
                    myp[row + g * 16 + l15] = (bf16)e;
                }
            }
            // P (C-layout rows) -> A-layout fragments (same wave, DS in-order)
            bf16x8 pa0 = load_bf8(myp + l15 * 72 + quad * 8);
            bf16x8 pa1 = load_bf8(myp + l15 * 72 + 32 + quad * 8);
            // ---- PV: 8 dim fragments x 2 key halves ----
#pragma unroll
            for (int f = 0; f < 8; ++f) {
                int dim = f * 16 + l15;
                int ch0 = quad ^ (l15 & 7);        // keys 0..31
                int ch1 = (4 + quad) ^ (l15 & 7);  // keys 32..63
                bf16x8 vb0 = load_bf8(sV + dim * 64 + ch0 * 8);
                bf16x8 vb1 = load_bf8(sV + dim * 64 + ch1 * 8);
                acc[f] = __builtin_amdgcn_mfma_f32_16x16x32_bf16(pa0, vb0, acc[f], 0, 0, 0);
                acc[f] = __builtin_amdgcn_mfma_f32_16x16x32_bf16(pa1, vb1, acc[f], 0, 0, 0);
            }
        }
        __syncthreads();
    }

    // one shuffle reduction at the end; fold sink; normalize; store
    float sk = __expf(sinks[h]);
#pragma unroll
    for (int r = 0; r < 4; ++r) {
        float rs = lpart[r];
#pragma unroll
        for (int o = 1; o < 16; o <<= 1) rs += __shfl_xor(rs, o, 64);
        float inv = 1.0f / (rs + sk);
        int m = qw0 + quad * 4 + r;
#pragma unroll
        for (int f = 0; f < 8; ++f) {
            attb[(size_t)m * 2048 + h * 128 + f * 16 + l15] = (bf16)(acc[f][r] * inv);
        }
    }
}

extern "C" void kernel_launch(void* const* d_in, const int* in_sizes, int n_in,
                              void* d_out, int out_size, void* d_ws, size_t ws_size,
                              hipStream_t stream) {
    const float* x      = (const float*)d_in[0];
    const float* w_q    = (const float*)d_in[1];
    const float* w_k    = (const float*)d_in[2];
    const float* w_v    = (const float*)d_in[3];
    const float* w_out  = (const float*)d_in[4];
    const float* q_norm = (const float*)d_in[5];
    const float* k_norm = (const float*)d_in[6];
    const float* sinks  = (const float*)d_in[7];

    char* ws = (char*)d_ws;
    const size_t MB = 1u << 20;
    bf16* xb   = (bf16*)(ws + 0 * MB);    // 8 MB
    bf16* wqb  = (bf16*)(ws + 8 * MB);    // 8 MB  (wqb/wkb/wvb contiguous)
    bf16* wkb  = (bf16*)(ws + 16 * MB);   // 2 MB  (forms wcomb [3072][2048])
    bf16* wvb  = (bf16*)(ws + 18 * MB);   // 2 MB
    bf16* wob  = (bf16*)(ws + 20 * MB);   // 8 MB
    bf16* qkv  = (bf16*)(ws + 28 * MB);   // 12 MB (S x 3072, post-clip)
    bf16* qb   = (bf16*)(ws + 40 * MB);   // 8 MB  (post norm+rope)
    bf16* kb   = (bf16*)(ws + 48 * MB);   // 2 MB
    bf16* vtb  = (bf16*)(ws + 50 * MB);   // 2 MB  (V transposed)
    bf16* attb = (bf16*)(ws + 52 * MB);   // 8 MB
    bf16* wcomb = wqb;                    // rows 0..3071 = [w_q; w_k; w_v]
    float* out = (float*)d_out;

    convert_kernel<<<14336, 256, 0, stream>>>(x, w_q, w_k, w_v, w_out,
                                              xb, wqb, wkb, wvb, wob);
    gemm128<true, bf16><<<dim3(24, 16), 256, 0, stream>>>(xb, wcomb, qkv, 3072, 2048);
    norm_rope<<<dim3(2048, 20), 128, 0, stream>>>(qkv, q_norm, k_norm, qb, kb, vtb);
    attn<<<dim3(32, 16), 256, 0, stream>>>(qb, kb, vtb, sinks, attb);
    gemm128<false, float><<<dim3(16, 16), 256, 0, stream>>>(attb, wob, out, 2048, 2048);
}

// Round 6
// 253.923 us; speedup vs baseline: 1.4429x; 1.0207x over previous
//
#include <hip/hip_runtime.h>
#include <hip/hip_bf16.h>
#include <math.h>

#define S_LEN 2048
#define DMODEL 2048
#define NH 16
#define NKVH 4
#define HDIM 128
#define WINDOW 1024

typedef __bf16 bf16;
typedef __bf16 bf16x8 __attribute__((ext_vector_type(8)));
typedef float floatx4 __attribute__((ext_vector_type(4)));

static __device__ __forceinline__ bf16x8 load_bf8(const bf16* p) {
    return *reinterpret_cast<const bf16x8*>(p);
}

// async 16B global->LDS (wave-uniform LDS base + lane*16)
static __device__ __forceinline__ void async16(const bf16* g, bf16* l) {
    __builtin_amdgcn_global_load_lds(
        (const __attribute__((address_space(1))) void*)g,
        (__attribute__((address_space(3))) void*)l, 16, 0, 0);
}

// ---------------- fp32 -> bf16 conversion of x and all weights ----------------
__global__ __launch_bounds__(256) void convert_kernel(
    const float* __restrict__ x, const float* __restrict__ wq,
    const float* __restrict__ wk, const float* __restrict__ wv,
    const float* __restrict__ wo,
    bf16* __restrict__ xb, bf16* __restrict__ wqb, bf16* __restrict__ wkb,
    bf16* __restrict__ wvb, bf16* __restrict__ wob) {
    int i = blockIdx.x * blockDim.x + threadIdx.x;  // one float4 per thread
    const float* src; bf16* dst; int off;
    if      (i < 1048576) { src = x;  dst = xb;  off = i; }
    else if (i < 2097152) { src = wq; dst = wqb; off = i - 1048576; }
    else if (i < 2359296) { src = wk; dst = wkb; off = i - 2097152; }
    else if (i < 2621440) { src = wv; dst = wvb; off = i - 2359296; }
    else if (i < 3670016) { src = wo; dst = wob; off = i - 2621440; }
    else return;
    float4 v = reinterpret_cast<const float4*>(src)[off];
    union { bf16 b[4]; ushort4 u; } t;
    t.b[0] = (bf16)v.x; t.b[1] = (bf16)v.y; t.b[2] = (bf16)v.z; t.b[3] = (bf16)v.w;
    reinterpret_cast<ushort4*>(dst)[off] = t.u;
}

// ------- 128x128-tile GEMM, double-buffered async staging: C = A @ B^T -------
// One barrier per k-iter; prefetch of tile k+1 issued after the barrier that
// opens compute on tile k, so its drain overlaps the whole compute body.
template <bool CLIP, typename OutT>
__global__ __launch_bounds__(256) void gemm128(
    const bf16* __restrict__ A, const bf16* __restrict__ B,
    OutT* __restrict__ C, int N, int K) {
    __shared__ __align__(16) bf16 sA[2][128 * 32];  // 16 KB
    __shared__ __align__(16) bf16 sB[2][128 * 32];  // 16 KB
    int tid = threadIdx.x;
    int lane = tid & 63, wid = tid >> 6;
    int l15 = lane & 15, quad = lane >> 4;
    int m0 = blockIdx.y * 128, n0 = blockIdx.x * 128;

    int srow = wid * 16 + (lane >> 2);
    int scol = (lane & 3) * 8;
    const bf16* gA0 = A + (size_t)(m0 + srow) * K + scol;
    const bf16* gA1 = gA0 + (size_t)64 * K;
    const bf16* gB0 = B + (size_t)(n0 + srow) * K + scol;
    const bf16* gB1 = gB0 + (size_t)64 * K;
    int lOfA = (wid * 16) * 32;          // wave-uniform LDS offsets
    int lOfB = (wid * 16) * 32;

    floatx4 acc[4][4];
#pragma unroll
    for (int mi = 0; mi < 4; ++mi)
#pragma unroll
        for (int ni = 0; ni < 4; ++ni) acc[mi][ni] = floatx4{0.f, 0.f, 0.f, 0.f};

    int mb = (wid & 1) * 64, nb = (wid >> 1) * 64;

    // prologue: stage tile 0 into buffer 0
    async16(gA0, sA[0] + lOfA);
    async16(gA1, sA[0] + 64 * 32 + lOfA);
    async16(gB0, sB[0] + lOfB);
    async16(gB1, sB[0] + 64 * 32 + lOfB);

    int buf = 0;
    for (int k0 = 0; k0 < K; k0 += 32) {
        __syncthreads();   // tile(buf) ready; buf^1 free (consumed last iter)
        if (k0 + 32 < K) { // prefetch next tile into buf^1
            async16(gA0 + k0 + 32, sA[buf ^ 1] + lOfA);
            async16(gA1 + k0 + 32, sA[buf ^ 1] + 64 * 32 + lOfA);
            async16(gB0 + k0 + 32, sB[buf ^ 1] + lOfB);
            async16(gB1 + k0 + 32, sB[buf ^ 1] + 64 * 32 + lOfB);
        }
        bf16x8 af[4], bq[4];
#pragma unroll
        for (int i = 0; i < 4; ++i) {
            af[i] = load_bf8(sA[buf] + (mb + i * 16 + l15) * 32 + quad * 8);
            bq[i] = load_bf8(sB[buf] + (nb + i * 16 + l15) * 32 + quad * 8);
        }
#pragma unroll
        for (int mi = 0; mi < 4; ++mi)
#pragma unroll
            for (int ni = 0; ni < 4; ++ni)
                acc[mi][ni] = __builtin_amdgcn_mfma_f32_16x16x32_bf16(
                    af[mi], bq[ni], acc[mi][ni], 0, 0, 0);
        buf ^= 1;
    }

#pragma unroll
    for (int mi = 0; mi < 4; ++mi)
#pragma unroll
        for (int ni = 0; ni < 4; ++ni)
#pragma unroll
            for (int r = 0; r < 4; ++r) {
                int m = m0 + mb + mi * 16 + quad * 4 + r;
                int n = n0 + nb + ni * 16 + l15;
                float v = acc[mi][ni][r];
                if (CLIP) v = fminf(fmaxf(v, -8.0f), 8.0f);
                C[(size_t)m * N + n] = (OutT)v;
            }
}

// ---------------- per-head RMSNorm + RoPE; V transposed copy -----------------
__global__ __launch_bounds__(128) void norm_rope(
    const bf16* __restrict__ qkv, const float* __restrict__ qw,
    const float* __restrict__ kw, bf16* __restrict__ qb,
    bf16* __restrict__ kb, bf16* __restrict__ vtb) {
    int s = blockIdx.x;
    int idx = blockIdx.y;      // 0..15 = q heads, 16..19 = k heads (+v copy)
    int d = threadIdx.x;       // 0..127
    bool isq = idx < 16;
    int off = isq ? idx * 128 : 2048 + (idx - 16) * 128;
    float val = (float)qkv[(size_t)s * 3072 + off + d];

    float ss = val * val;
#pragma unroll
    for (int o = 32; o > 0; o >>= 1) ss += __shfl_xor(ss, o, 64);
    __shared__ float wsum[2];
    __shared__ float xs[128];
    if ((threadIdx.x & 63) == 0) wsum[threadIdx.x >> 6] = ss;
    __syncthreads();
    float var = (wsum[0] + wsum[1]) * (1.0f / 128.0f);
    float nw = isq ? qw[d] : kw[d];
    float xn = val * rsqrtf(var + 1e-6f) * nw;
    xs[d] = xn;
    __syncthreads();
    float part = xs[d ^ 64];
    float rot = (d < 64) ? -part : part;
    int fi = d & 63;
    // inv_freq = theta^(-fi/64); ln(500000) = 13.122363377404328
    float inv = __expf((float)fi * (-13.122363377404328f / 64.0f));
    float ang = (float)s * inv;
    float c = __cosf(ang), sn = __sinf(ang);
    float outv = xn * c + rot * sn;
    if (isq) {
        qb[(size_t)s * 2048 + idx * 128 + d] = (bf16)outv;
    } else {
        int kh = idx - 16;
        kb[(size_t)s * 512 + kh * 128 + d] = (bf16)outv;
        bf16 vv = qkv[(size_t)s * 3072 + 2560 + kh * 128 + d];
        vtb[((size_t)(kh * 128 + d)) * 2048 + s] = vv;  // V^T: [kvh*128+d][s]
    }
}

// -------- flash attention: double-buffered LDS K/V, fixed-m softmax ----------
__global__ __launch_bounds__(256) void attn(
    const bf16* __restrict__ qb, const bf16* __restrict__ kb,
    const bf16* __restrict__ vtb, const float* __restrict__ sinks,
    bf16* __restrict__ attb) {
    __shared__ __align__(16) bf16 sK[2][64 * 128];   // 32 KB, swizzled
    __shared__ __align__(16) bf16 sV[2][128 * 64];   // 32 KB, swizzled
    __shared__ __align__(16) bf16 sP[4][16 * 72];    // 9 KB per-wave P, padded
    int tid = threadIdx.x;
    int lane = tid & 63, wid = tid >> 6;
    int l15 = lane & 15, quad = lane >> 4;
    int h = blockIdx.y, kh = h >> 2;
    int bq0 = blockIdx.x * 64;
    int qw0 = bq0 + wid * 16;
    bf16* myp = sP[wid];

    // Q fragments: A[m=l15][k=quad*8+j], 4 chunks of k=32 covering HD=128
    bf16x8 qf[4];
    const bf16* qrow = qb + (size_t)(qw0 + l15) * 2048 + h * 128 + quad * 8;
#pragma unroll
    for (int kc = 0; kc < 4; ++kc) qf[kc] = load_bf8(qrow + kc * 32);

    floatx4 acc[8];
#pragma unroll
    for (int f = 0; f < 8; ++f) acc[f] = floatx4{0.f, 0.f, 0.f, 0.f};
    float lpart[4] = {0.f, 0.f, 0.f, 0.f};
    int qi_base = qw0 + quad * 4;

    // staging source columns (XOR chunk swizzle; LDS dest forced = lane*16)
    int keyit = wid * 4 + (lane >> 4);              // key-in-tile mod 16
    int gcK = (lane & 15) ^ keyit;                  // K: 16-chunk rows
    int dimit = wid * 8 + (lane >> 3);              // dim-in-round (0..31)
    int gcV = (lane & 7) ^ ((lane >> 3) & 7);       // V: 8-chunk rows

    int tstart = bq0 - 1024; if (tstart < 0) tstart = 0;
    const bf16* kbase = kb + (size_t)kh * 128;
    const bf16* vbase = vtb + (size_t)kh * 128 * 2048;

    // prologue: stage first tile into buffer 0
#pragma unroll
    for (int r = 0; r < 4; ++r) {
        async16(kbase + (size_t)(tstart + r * 16 + keyit) * 512 + gcK * 8,
                sK[0] + (r * 16 + wid * 4) * 128);
        async16(vbase + (size_t)(r * 32 + dimit) * 2048 + tstart + gcV * 8,
                sV[0] + (r * 32 + wid * 8) * 64);
    }

    int buf = 0;
    for (int t = tstart; t <= bq0; t += 64) {
        __syncthreads();   // tile(buf) ready; buf^1 consumed
        if (t + 64 <= bq0) {
#pragma unroll
            for (int r = 0; r < 4; ++r) {
                async16(kbase + (size_t)(t + 64 + r * 16 + keyit) * 512 + gcK * 8,
                        sK[buf ^ 1] + (r * 16 + wid * 4) * 128);
                async16(vbase + (size_t)(r * 32 + dimit) * 2048 + t + 64 + gcV * 8,
                        sV[buf ^ 1] + (r * 32 + wid * 8) * 64);
            }
        }
        bool active = !((t + 63 <= qw0 - WINDOW) || (t > qw0 + 15));
        if (active) {
            // ---- QK^T: 4 key groups x 4 k-chunks ----
            floatx4 s[4];
#pragma unroll
            for (int g = 0; g < 4; ++g) s[g] = floatx4{0.f, 0.f, 0.f, 0.f};
#pragma unroll
            for (int g = 0; g < 4; ++g) {
                int key = g * 16 + l15;
#pragma unroll
                for (int kc = 0; kc < 4; ++kc) {
                    int ch = (kc * 4 + quad) ^ l15;  // unswizzle
                    bf16x8 b = load_bf8(sK[buf] + key * 128 + ch * 8);
                    s[g] = __builtin_amdgcn_mfma_f32_16x16x32_bf16(qf[kc], b, s[g], 0, 0, 0);
                }
            }
            // ---- scale+mask+exp -> P (padded LDS), partial row sums ----
#pragma unroll
            for (int r = 0; r < 4; ++r) {
                int qi = qi_base + r;
                int row = (quad * 4 + r) * 72;
#pragma unroll
                for (int g = 0; g < 4; ++g) {
                    int ki = t + g * 16 + l15;
                    float v = s[g][r] * 0.08838834764831845f;  // 1/sqrt(128)
                    bool ok = (ki <= qi) && (ki > qi - WINDOW);
                    float e = ok ? __expf(v) : 0.0f;
                    lpart[r] += e;
                    myp[row + g * 16 + l15] = (bf16)e;
                }
            }
            // P (C-layout rows) -> A-layout fragments (same wave, DS in-order)
            bf16x8 pa0 = load_bf8(myp + l15 * 72 + quad * 8);
            bf16x8 pa1 = load_bf8(myp + l15 * 72 + 32 + quad * 8);
            // ---- PV: 8 dim fragments x 2 key halves ----
#pragma unroll
            for (int f = 0; f < 8; ++f) {
                int dim = f * 16 + l15;
                int ch0 = quad ^ (l15 & 7);        // keys 0..31
                int ch1 = (4 + quad) ^ (l15 & 7);  // keys 32..63
                bf16x8 vb0 = load_bf8(sV[buf] + dim * 64 + ch0 * 8);
                bf16x8 vb1 = load_bf8(sV[buf] + dim * 64 + ch1 * 8);
                acc[f] = __builtin_amdgcn_mfma_f32_16x16x32_bf16(pa0, vb0, acc[f], 0, 0, 0);
                acc[f] = __builtin_amdgcn_mfma_f32_16x16x32_bf16(pa1, vb1, acc[f], 0, 0, 0);
            }
        }
        buf ^= 1;
    }

    // one shuffle reduction at the end; fold sink; normalize; store
    float sk = __expf(sinks[h]);
#pragma unroll
    for (int r = 0; r < 4; ++r) {
        float rs = lpart[r];
#pragma unroll
        for (int o = 1; o < 16; o <<= 1) rs += __shfl_xor(rs, o, 64);
        float inv = 1.0f / (rs + sk);
        int m = qw0 + quad * 4 + r;
#pragma unroll
        for (int f = 0; f < 8; ++f) {
            attb[(size_t)m * 2048 + h * 128 + f * 16 + l15] = (bf16)(acc[f][r] * inv);
        }
    }
}

extern "C" void kernel_launch(void* const* d_in, const int* in_sizes, int n_in,
                              void* d_out, int out_size, void* d_ws, size_t ws_size,
                              hipStream_t stream) {
    const float* x      = (const float*)d_in[0];
    const float* w_q    = (const float*)d_in[1];
    const float* w_k    = (const float*)d_in[2];
    const float* w_v    = (const float*)d_in[3];
    const float* w_out  = (const float*)d_in[4];
    const float* q_norm = (const float*)d_in[5];
    const float* k_norm = (const float*)d_in[6];
    const float* sinks  = (const float*)d_in[7];

    char* ws = (char*)d_ws;
    const size_t MB = 1u << 20;
    bf16* xb   = (bf16*)(ws + 0 * MB);    // 8 MB
    bf16* wqb  = (bf16*)(ws + 8 * MB);    // 8 MB  (wqb/wkb/wvb contiguous)
    bf16* wkb  = (bf16*)(ws + 16 * MB);   // 2 MB  (forms wcomb [3072][2048])
    bf16* wvb  = (bf16*)(ws + 18 * MB);   // 2 MB
    bf16* wob  = (bf16*)(ws + 20 * MB);   // 8 MB
    bf16* qkv  = (bf16*)(ws + 28 * MB);   // 12 MB (S x 3072, post-clip)
    bf16* qb   = (bf16*)(ws + 40 * MB);   // 8 MB  (post norm+rope)
    bf16* kb   = (bf16*)(ws + 48 * MB);   // 2 MB
    bf16* vtb  = (bf16*)(ws + 50 * MB);   // 2 MB  (V transposed)
    bf16* attb = (bf16*)(ws + 52 * MB);   // 8 MB
    bf16* wcomb = wqb;                    // rows 0..3071 = [w_q; w_k; w_v]
    float* out = (float*)d_out;

    convert_kernel<<<14336, 256, 0, stream>>>(x, w_q, w_k, w_v, w_out,
                                              xb, wqb, wkb, wvb, wob);
    gemm128<true, bf16><<<dim3(24, 16), 256, 0, stream>>>(xb, wcomb, qkv, 3072, 2048);
    norm_rope<<<dim3(2048, 20), 128, 0, stream>>>(qkv, q_norm, k_norm, qb, kb, vtb);
    attn<<<dim3(32, 16), 256, 0, stream>>>(qb, kb, vtb, sinks, attb);
    gemm128<false, float><<<dim3(16, 16), 256, 0, stream>>>(attb, wob, out, 2048, 2048);
}

// Round 7
// 223.237 us; speedup vs baseline: 1.6413x; 1.1375x over previous
//
#include <hip/hip_runtime.h>
#include <hip/hip_bf16.h>
#include <math.h>

#define S_LEN 2048
#define DMODEL 2048
#define NH 16
#define NKVH 4
#define HDIM 128
#define WINDOW 1024

typedef __bf16 bf16;
typedef __bf16 bf16x8 __attribute__((ext_vector_type(8)));
typedef float floatx4 __attribute__((ext_vector_type(4)));

static __device__ __forceinline__ bf16x8 load_bf8(const bf16* p) {
    return *reinterpret_cast<const bf16x8*>(p);
}

// async 16B global->LDS (wave-uniform LDS base + lane*16)
static __device__ __forceinline__ void async16(const bf16* g, bf16* l) {
    __builtin_amdgcn_global_load_lds(
        (const __attribute__((address_space(1))) void*)g,
        (__attribute__((address_space(3))) void*)l, 16, 0, 0);
}

// ---------------- fp32 -> bf16 conversion of x and all weights ----------------
__global__ __launch_bounds__(256) void convert_kernel(
    const float* __restrict__ x, const float* __restrict__ wq,
    const float* __restrict__ wk, const float* __restrict__ wv,
    const float* __restrict__ wo,
    bf16* __restrict__ xb, bf16* __restrict__ wqb, bf16* __restrict__ wkb,
    bf16* __restrict__ wvb, bf16* __restrict__ wob) {
    int i = blockIdx.x * blockDim.x + threadIdx.x;  // one float4 per thread
    const float* src; bf16* dst; int off;
    if      (i < 1048576) { src = x;  dst = xb;  off = i; }
    else if (i < 2097152) { src = wq; dst = wqb; off = i - 1048576; }
    else if (i < 2359296) { src = wk; dst = wkb; off = i - 2097152; }
    else if (i < 2621440) { src = wv; dst = wvb; off = i - 2359296; }
    else if (i < 3670016) { src = wo; dst = wob; off = i - 2621440; }
    else return;
    float4 v = reinterpret_cast<const float4*>(src)[off];
    union { bf16 b[4]; ushort4 u; } t;
    t.b[0] = (bf16)v.x; t.b[1] = (bf16)v.y; t.b[2] = (bf16)v.z; t.b[3] = (bf16)v.w;
    reinterpret_cast<ushort4*>(dst)[off] = t.u;
}

// ===== QKV GEMM (64x128 tile, dbuf) + fused clip + RMSNorm + RoPE ============
// One 128-col N-tile == one head (HD=128). q: n<2048 -> qb; k: 2048..2559 ->
// kb; v: >=2560 -> clipped transpose into vtb. Norm/rope in fp32.
__global__ __launch_bounds__(256) void gemm_qkv_fused(
    const bf16* __restrict__ A, const bf16* __restrict__ B,
    const float* __restrict__ qw, const float* __restrict__ kw,
    bf16* __restrict__ qb, bf16* __restrict__ kb, bf16* __restrict__ vtb) {
    const int K = 2048;
    __shared__ __align__(16) bf16 sA[2][64 * 32];    // 8 KB
    __shared__ __align__(16) bf16 sB[2][128 * 32];   // 16 KB
    __shared__ float rowss[64][2];                   // per-row sum-of-squares
    __shared__ bf16 xnorm[64][128];                  // normalized tile, 16 KB
    int tid = threadIdx.x;
    int lane = tid & 63, wid = tid >> 6;
    int l15 = lane & 15, quad = lane >> 4;
    int m0 = blockIdx.y * 64, n0 = blockIdx.x * 128;

    int srow = wid * 16 + (lane >> 2);
    int scol = (lane & 3) * 8;
    const bf16* gA  = A + (size_t)(m0 + srow) * K + scol;
    const bf16* gB0 = B + (size_t)(n0 + srow) * K + scol;
    const bf16* gB1 = gB0 + (size_t)64 * K;
    int lOfA = (wid * 16) * 32;
    int lOfB = (wid * 16) * 32;

    floatx4 acc[2][4];
#pragma unroll
    for (int mi = 0; mi < 2; ++mi)
#pragma unroll
        for (int ni = 0; ni < 4; ++ni) acc[mi][ni] = floatx4{0.f, 0.f, 0.f, 0.f};

    int mb = (wid & 1) * 32, nb = (wid >> 1) * 64;

    async16(gA, sA[0] + lOfA);
    async16(gB0, sB[0] + lOfB);
    async16(gB1, sB[0] + 64 * 32 + lOfB);

    int buf = 0;
    for (int k0 = 0; k0 < K; k0 += 32) {
        __syncthreads();
        if (k0 + 32 < K) {
            async16(gA + k0 + 32, sA[buf ^ 1] + lOfA);
            async16(gB0 + k0 + 32, sB[buf ^ 1] + lOfB);
            async16(gB1 + k0 + 32, sB[buf ^ 1] + 64 * 32 + lOfB);
        }
        bf16x8 af[2], bq[4];
#pragma unroll
        for (int i = 0; i < 2; ++i)
            af[i] = load_bf8(sA[buf] + (mb + i * 16 + l15) * 32 + quad * 8);
#pragma unroll
        for (int i = 0; i < 4; ++i)
            bq[i] = load_bf8(sB[buf] + (nb + i * 16 + l15) * 32 + quad * 8);
#pragma unroll
        for (int mi = 0; mi < 2; ++mi)
#pragma unroll
            for (int ni = 0; ni < 4; ++ni)
                acc[mi][ni] = __builtin_amdgcn_mfma_f32_16x16x32_bf16(
                    af[mi], bq[ni], acc[mi][ni], 0, 0, 0);
        buf ^= 1;
    }

    // ---- clip (all outputs) ----
#pragma unroll
    for (int mi = 0; mi < 2; ++mi)
#pragma unroll
        for (int ni = 0; ni < 4; ++ni)
#pragma unroll
            for (int r = 0; r < 4; ++r)
                acc[mi][ni][r] = fminf(fmaxf(acc[mi][ni][r], -8.0f), 8.0f);

    if (n0 >= 2560) {  // V: transpose-store, no norm/rope
#pragma unroll
        for (int mi = 0; mi < 2; ++mi)
#pragma unroll
            for (int ni = 0; ni < 4; ++ni)
#pragma unroll
                for (int r = 0; r < 4; ++r) {
                    int row = m0 + mb + mi * 16 + quad * 4 + r;
                    int n = n0 + nb + ni * 16 + l15;
                    vtb[(size_t)(n - 2560) * 2048 + row] = (bf16)acc[mi][ni][r];
                }
        return;
    }

    // ---- per-row sum of squares (row spans two wave n-halves) ----
#pragma unroll
    for (int mi = 0; mi < 2; ++mi)
#pragma unroll
        for (int r = 0; r < 4; ++r) {
            float s = 0.f;
#pragma unroll
            for (int ni = 0; ni < 4; ++ni) s += acc[mi][ni][r] * acc[mi][ni][r];
#pragma unroll
            for (int o = 1; o < 16; o <<= 1) s += __shfl_xor(s, o, 64);
            if (l15 == 0) rowss[mb + mi * 16 + quad * 4 + r][wid >> 1] = s;
        }
    __syncthreads();

    // ---- normalize (fp32), stash weighted-normalized tile for rope pairing --
    const float* nw = (n0 < 2048) ? qw : kw;
#pragma unroll
    for (int mi = 0; mi < 2; ++mi)
#pragma unroll
        for (int r = 0; r < 4; ++r) {
            int row = mb + mi * 16 + quad * 4 + r;
            float var = (rowss[row][0] + rowss[row][1]) * (1.0f / 128.0f);
            float rinv = rsqrtf(var + 1e-6f);
#pragma unroll
            for (int ni = 0; ni < 4; ++ni) {
                int col = nb + ni * 16 + l15;
                float xn = acc[mi][ni][r] * rinv * nw[col];
                acc[mi][ni][r] = xn;
                xnorm[row][col] = (bf16)xn;
            }
        }
    __syncthreads();

    // ---- RoPE + store ----
    float invf[4];
#pragma unroll
    for (int ni = 0; ni < 4; ++ni) {
        int fi = (nb + ni * 16 + l15) & 63;
        invf[ni] = __expf((float)fi * (-13.122363377404328f / 64.0f));
    }
    bool lowhalf = (nb == 0);  // wave-uniform: cols 0..63 vs 64..127
#pragma unroll
    for (int mi = 0; mi < 2; ++mi)
#pragma unroll
        for (int r = 0; r < 4; ++r) {
            int row = mb + mi * 16 + quad * 4 + r;
            float pos = (float)(m0 + row);
#pragma unroll
            for (int ni = 0; ni < 4; ++ni) {
                int col = nb + ni * 16 + l15;
                float ang = pos * invf[ni];
                float c = __cosf(ang), sn = __sinf(ang);
                float part = (float)xnorm[row][col ^ 64];
                float rot = lowhalf ? -part : part;
                float o = acc[mi][ni][r] * c + rot * sn;
                int n = n0 + col;
                int s = m0 + row;
                if (n0 < 2048) qb[(size_t)s * 2048 + n] = (bf16)o;
                else           kb[(size_t)s * 512 + (n - 2048)] = (bf16)o;
            }
        }
}

// ---------- out-proj GEMM: 64x128 tile, dbuf, C = A @ B^T (fp32 out) --------
__global__ __launch_bounds__(256) void gemm_out(
    const bf16* __restrict__ A, const bf16* __restrict__ B,
    float* __restrict__ C) {
    const int K = 2048, N = 2048;
    __shared__ __align__(16) bf16 sA[2][64 * 32];
    __shared__ __align__(16) bf16 sB[2][128 * 32];
    int tid = threadIdx.x;
    int lane = tid & 63, wid = tid >> 6;
    int l15 = lane & 15, quad = lane >> 4;
    int m0 = blockIdx.y * 64, n0 = blockIdx.x * 128;

    int srow = wid * 16 + (lane >> 2);
    int scol = (lane & 3) * 8;
    const bf16* gA  = A + (size_t)(m0 + srow) * K + scol;
    const bf16* gB0 = B + (size_t)(n0 + srow) * K + scol;
    const bf16* gB1 = gB0 + (size_t)64 * K;
    int lOfA = (wid * 16) * 32;
    int lOfB = (wid * 16) * 32;

    floatx4 acc[2][4];
#pragma unroll
    for (int mi = 0; mi < 2; ++mi)
#pragma unroll
        for (int ni = 0; ni < 4; ++ni) acc[mi][ni] = floatx4{0.f, 0.f, 0.f, 0.f};

    int mb = (wid & 1) * 32, nb = (wid >> 1) * 64;

    async16(gA, sA[0] + lOfA);
    async16(gB0, sB[0] + lOfB);
    async16(gB1, sB[0] + 64 * 32 + lOfB);

    int buf = 0;
    for (int k0 = 0; k0 < K; k0 += 32) {
        __syncthreads();
        if (k0 + 32 < K) {
            async16(gA + k0 + 32, sA[buf ^ 1] + lOfA);
            async16(gB0 + k0 + 32, sB[buf ^ 1] + lOfB);
            async16(gB1 + k0 + 32, sB[buf ^ 1] + 64 * 32 + lOfB);
        }
        bf16x8 af[2], bq[4];
#pragma unroll
        for (int i = 0; i < 2; ++i)
            af[i] = load_bf8(sA[buf] + (mb + i * 16 + l15) * 32 + quad * 8);
#pragma unroll
        for (int i = 0; i < 4; ++i)
            bq[i] = load_bf8(sB[buf] + (nb + i * 16 + l15) * 32 + quad * 8);
#pragma unroll
        for (int mi = 0; mi < 2; ++mi)
#pragma unroll
            for (int ni = 0; ni < 4; ++ni)
                acc[mi][ni] = __builtin_amdgcn_mfma_f32_16x16x32_bf16(
                    af[mi], bq[ni], acc[mi][ni], 0, 0, 0);
        buf ^= 1;
    }

#pragma unroll
    for (int mi = 0; mi < 2; ++mi)
#pragma unroll
        for (int ni = 0; ni < 4; ++ni)
#pragma unroll
            for (int r = 0; r < 4; ++r) {
                int m = m0 + mb + mi * 16 + quad * 4 + r;
                int n = n0 + nb + ni * 16 + l15;
                C[(size_t)m * N + n] = acc[mi][ni][r];
            }
}

// -------- flash attention: double-buffered LDS K/V, fixed-m softmax ----------
__global__ __launch_bounds__(256) void attn(
    const bf16* __restrict__ qb, const bf16* __restrict__ kb,
    const bf16* __restrict__ vtb, const float* __restrict__ sinks,
    bf16* __restrict__ attb) {
    __shared__ __align__(16) bf16 sK[2][64 * 128];   // 32 KB, swizzled
    __shared__ __align__(16) bf16 sV[2][128 * 64];   // 32 KB, swizzled
    __shared__ __align__(16) bf16 sP[4][16 * 72];    // 9 KB per-wave P, padded
    int tid = threadIdx.x;
    int lane = tid & 63, wid = tid >> 6;
    int l15 = lane & 15, quad = lane >> 4;
    int h = blockIdx.y, kh = h >> 2;
    int bq0 = blockIdx.x * 64;
    int qw0 = bq0 + wid * 16;
    bf16* myp = sP[wid];

    bf16x8 qf[4];
    const bf16* qrow = qb + (size_t)(qw0 + l15) * 2048 + h * 128 + quad * 8;
#pragma unroll
    for (int kc = 0; kc < 4; ++kc) qf[kc] = load_bf8(qrow + kc * 32);

    floatx4 acc[8];
#pragma unroll
    for (int f = 0; f < 8; ++f) acc[f] = floatx4{0.f, 0.f, 0.f, 0.f};
    float lpart[4] = {0.f, 0.f, 0.f, 0.f};
    int qi_base = qw0 + quad * 4;

    int keyit = wid * 4 + (lane >> 4);
    int gcK = (lane & 15) ^ keyit;
    int dimit = wid * 8 + (lane >> 3);
    int gcV = (lane & 7) ^ ((lane >> 3) & 7);

    int tstart = bq0 - 1024; if (tstart < 0) tstart = 0;
    const bf16* kbase = kb + (size_t)kh * 128;
    const bf16* vbase = vtb + (size_t)kh * 128 * 2048;

#pragma unroll
    for (int r = 0; r < 4; ++r) {
        async16(kbase + (size_t)(tstart + r * 16 + keyit) * 512 + gcK * 8,
                sK[0] + (r * 16 + wid * 4) * 128);
        async16(vbase + (size_t)(r * 32 + dimit) * 2048 + tstart + gcV * 8,
                sV[0] + (r * 32 + wid * 8) * 64);
    }

    int buf = 0;
    for (int t = tstart; t <= bq0; t += 64) {
        __syncthreads();
        if (t + 64 <= bq0) {
#pragma unroll
            for (int r = 0; r < 4; ++r) {
                async16(kbase + (size_t)(t + 64 + r * 16 + keyit) * 512 + gcK * 8,
                        sK[buf ^ 1] + (r * 16 + wid * 4) * 128);
                async16(vbase + (size_t)(r * 32 + dimit) * 2048 + t + 64 + gcV * 8,
                        sV[buf ^ 1] + (r * 32 + wid * 8) * 64);
            }
        }
        bool active = !((t + 63 <= qw0 - WINDOW) || (t > qw0 + 15));
        if (active) {
            floatx4 s[4];
#pragma unroll
            for (int g = 0; g < 4; ++g) s[g] = floatx4{0.f, 0.f, 0.f, 0.f};
#pragma unroll
            for (int g = 0; g < 4; ++g) {
                int key = g * 16 + l15;
#pragma unroll
                for (int kc = 0; kc < 4; ++kc) {
                    int ch = (kc * 4 + quad) ^ l15;
                    bf16x8 b = load_bf8(sK[buf] + key * 128 + ch * 8);
                    s[g] = __builtin_amdgcn_mfma_f32_16x16x32_bf16(qf[kc], b, s[g], 0, 0, 0);
                }
            }
#pragma unroll
            for (int r = 0; r < 4; ++r) {
                int qi = qi_base + r;
                int row = (quad * 4 + r) * 72;
#pragma unroll
                for (int g = 0; g < 4; ++g) {
                    int ki = t + g * 16 + l15;
                    float v = s[g][r] * 0.08838834764831845f;
                    bool ok = (ki <= qi) && (ki > qi - WINDOW);
                    float e = ok ? __expf(v) : 0.0f;
                    lpart[r] += e;
                    myp[row + g * 16 + l15] = (bf16)e;
                }
            }
            bf16x8 pa0 = load_bf8(myp + l15 * 72 + quad * 8);
            bf16x8 pa1 = load_bf8(myp + l15 * 72 + 32 + quad * 8);
#pragma unroll
            for (int f = 0; f < 8; ++f) {
                int dim = f * 16 + l15;
                int ch0 = quad ^ (l15 & 7);
                int ch1 = (4 + quad) ^ (l15 & 7);
                bf16x8 vb0 = load_bf8(sV[buf] + dim * 64 + ch0 * 8);
                bf16x8 vb1 = load_bf8(sV[buf] + dim * 64 + ch1 * 8);
                acc[f] = __builtin_amdgcn_mfma_f32_16x16x32_bf16(pa0, vb0, acc[f], 0, 0, 0);
                acc[f] = __builtin_amdgcn_mfma_f32_16x16x32_bf16(pa1, vb1, acc[f], 0, 0, 0);
            }
        }
        buf ^= 1;
    }

    float sk = __expf(sinks[h]);
#pragma unroll
    for (int r = 0; r < 4; ++r) {
        float rs = lpart[r];
#pragma unroll
        for (int o = 1; o < 16; o <<= 1) rs += __shfl_xor(rs, o, 64);
        float inv = 1.0f / (rs + sk);
        int m = qw0 + quad * 4 + r;
#pragma unroll
        for (int f = 0; f < 8; ++f) {
            attb[(size_t)m * 2048 + h * 128 + f * 16 + l15] = (bf16)(acc[f][r] * inv);
        }
    }
}

extern "C" void kernel_launch(void* const* d_in, const int* in_sizes, int n_in,
                              void* d_out, int out_size, void* d_ws, size_t ws_size,
                              hipStream_t stream) {
    const float* x      = (const float*)d_in[0];
    const float* w_q    = (const float*)d_in[1];
    const float* w_k    = (const float*)d_in[2];
    const float* w_v    = (const float*)d_in[3];
    const float* w_out  = (const float*)d_in[4];
    const float* q_norm = (const float*)d_in[5];
    const float* k_norm = (const float*)d_in[6];
    const float* sinks  = (const float*)d_in[7];

    char* ws = (char*)d_ws;
    const size_t MB = 1u << 20;
    bf16* xb   = (bf16*)(ws + 0 * MB);    // 8 MB
    bf16* wqb  = (bf16*)(ws + 8 * MB);    // 8 MB  (wqb/wkb/wvb contiguous)
    bf16* wkb  = (bf16*)(ws + 16 * MB);   // 2 MB  (forms wcomb [3072][2048])
    bf16* wvb  = (bf16*)(ws + 18 * MB);   // 2 MB
    bf16* wob  = (bf16*)(ws + 20 * MB);   // 8 MB
    bf16* qb   = (bf16*)(ws + 28 * MB);   // 8 MB  (post norm+rope)
    bf16* kb   = (bf16*)(ws + 36 * MB);   // 2 MB
    bf16* vtb  = (bf16*)(ws + 38 * MB);   // 2 MB  (V transposed)
    bf16* attb = (bf16*)(ws + 40 * MB);   // 8 MB
    bf16* wcomb = wqb;                    // rows 0..3071 = [w_q; w_k; w_v]
    float* out = (float*)d_out;

    convert_kernel<<<14336, 256, 0, stream>>>(x, w_q, w_k, w_v, w_out,
                                              xb, wqb, wkb, wvb, wob);
    gemm_qkv_fused<<<dim3(24, 32), 256, 0, stream>>>(xb, wcomb, q_norm, k_norm,
                                                     qb, kb, vtb);
    attn<<<dim3(32, 16), 256, 0, stream>>>(qb, kb, vtb, sinks, attb);
    gemm_out<<<dim3(16, 32), 256, 0, stream>>>(attb, wob, out);
}

// Round 9
// 211.550 us; speedup vs baseline: 1.7319x; 1.0552x over previous
//
#include <hip/hip_runtime.h>
#include <hip/hip_bf16.h>
#include <math.h>

#define S_LEN 2048
#define DMODEL 2048
#define NH 16
#define NKVH 4
#define HDIM 128
#define WINDOW 1024

typedef __bf16 bf16;
typedef __bf16 bf16x8 __attribute__((ext_vector_type(8)));
typedef float floatx4 __attribute__((ext_vector_type(4)));

static __device__ __forceinline__ bf16x8 load_bf8(const bf16* p) {
    return *reinterpret_cast<const bf16x8*>(p);
}

// async 16B global->LDS (wave-uniform LDS base + lane*16)
static __device__ __forceinline__ void async16(const bf16* g, bf16* l) {
    __builtin_amdgcn_global_load_lds(
        (const __attribute__((address_space(1))) void*)g,
        (__attribute__((address_space(3))) void*)l, 16, 0, 0);
}

// ---------------- fp32 -> bf16 conversion of x and all weights ----------------
__global__ __launch_bounds__(256) void convert_kernel(
    const float* __restrict__ x, const float* __restrict__ wq,
    const float* __restrict__ wk, const float* __restrict__ wv,
    const float* __restrict__ wo,
    bf16* __restrict__ xb, bf16* __restrict__ wqb, bf16* __restrict__ wkb,
    bf16* __restrict__ wvb, bf16* __restrict__ wob) {
    int i = blockIdx.x * blockDim.x + threadIdx.x;  // one float4 per thread
    const float* src; bf16* dst; int off;
    if      (i < 1048576) { src = x;  dst = xb;  off = i; }
    else if (i < 2097152) { src = wq; dst = wqb; off = i - 1048576; }
    else if (i < 2359296) { src = wk; dst = wkb; off = i - 2097152; }
    else if (i < 2621440) { src = wv; dst = wvb; off = i - 2359296; }
    else if (i < 3670016) { src = wo; dst = wob; off = i - 2621440; }
    else return;
    float4 v = reinterpret_cast<const float4*>(src)[off];
    union { bf16 b[4]; ushort4 u; } t;
    t.b[0] = (bf16)v.x; t.b[1] = (bf16)v.y; t.b[2] = (bf16)v.z; t.b[3] = (bf16)v.w;
    reinterpret_cast<ushort4*>(dst)[off] = t.u;
}

// ====== 128x128 tile, BK=64, dbuf GEMM body (32 MFMA/wave per barrier) =======
// LDS per buffer: A at smem+buf*8192, B at smem+16384+buf*8192.
// Layout: [128 rows][8 chunks of 8 elems], chunk XOR-swizzled by (row&7).
// Staging: wave w, instr j covers rows w*32 + j*8 + lane/8.
#define GEMM_BODY(EXTRA_LDS_DECLS)                                             \
    __shared__ __align__(16) bf16 smem[4 * 128 * 64]; /* 64 KB */              \
    EXTRA_LDS_DECLS                                                            \
    int tid = threadIdx.x;                                                     \
    int lane = tid & 63, wid = tid >> 6;                                       \
    int l15 = lane & 15, quad = lane >> 4;                                     \
    int rlocal = lane >> 3;                                                    \
    int scol = ((lane & 7) ^ rlocal) * 8;                                      \
    const bf16* gA = A + (size_t)(m0 + wid * 32 + rlocal) * K + scol;          \
    const bf16* gB = B + (size_t)(n0 + wid * 32 + rlocal) * K + scol;          \
    int ldsOf = (wid * 32) * 64;                                               \
    floatx4 acc[4][4];                                                         \
    _Pragma("unroll") for (int mi = 0; mi < 4; ++mi)                           \
        _Pragma("unroll") for (int ni = 0; ni < 4; ++ni)                       \
            acc[mi][ni] = floatx4{0.f, 0.f, 0.f, 0.f};                         \
    int mb = (wid & 1) * 64, nb = (wid >> 1) * 64;                             \
    _Pragma("unroll") for (int j = 0; j < 4; ++j) {                            \
        async16(gA + (size_t)(j * 8) * K, smem + ldsOf + j * 512);             \
        async16(gB + (size_t)(j * 8) * K, smem + 16384 + ldsOf + j * 512);     \
    }                                                                          \
    int buf = 0;                                                               \
    for (int k0 = 0; k0 < K; k0 += 64) {                                       \
        __syncthreads();                                                       \
        if (k0 + 64 < K) {                                                     \
            int nof = (buf ^ 1) * 8192;                                        \
            _Pragma("unroll") for (int j = 0; j < 4; ++j) {                    \
                async16(gA + (size_t)(j * 8) * K + k0 + 64,                    \
                        smem + nof + ldsOf + j * 512);                         \
                async16(gB + (size_t)(j * 8) * K + k0 + 64,                    \
                        smem + 16384 + nof + ldsOf + j * 512);                 \
            }                                                                  \
        }                                                                      \
        const bf16* sA = smem + buf * 8192;                                    \
        const bf16* sB = smem + 16384 + buf * 8192;                            \
        _Pragma("unroll") for (int kc = 0; kc < 2; ++kc) {                     \
            bf16x8 af[4], bq[4];                                               \
            _Pragma("unroll") for (int i = 0; i < 4; ++i) {                    \
                int ch = ((kc << 2) + quad) ^ (l15 & 7);                       \
                af[i] = load_bf8(sA + (mb + i * 16 + l15) * 64 + ch * 8);      \
                bq[i] = load_bf8(sB + (nb + i * 16 + l15) * 64 + ch * 8);      \
            }                                                                  \
            _Pragma("unroll") for (int mi = 0; mi < 4; ++mi)                   \
                _Pragma("unroll") for (int ni = 0; ni < 4; ++ni)               \
                    acc[mi][ni] = __builtin_amdgcn_mfma_f32_16x16x32_bf16(     \
                        af[mi], bq[ni], acc[mi][ni], 0, 0, 0);                 \
        }                                                                      \
        buf ^= 1;                                                              \
    }

// ===== QKV GEMM + fused clip + RMSNorm + RoPE (N-tile 128 == one head) ======
__global__ __launch_bounds__(256) void gemm_qkv_fused(
    const bf16* __restrict__ A, const bf16* __restrict__ B,
    const float* __restrict__ qw, const float* __restrict__ kw,
    bf16* __restrict__ qb, bf16* __restrict__ kb, bf16* __restrict__ vtb) {
    const int K = 2048;
    int m0 = blockIdx.y * 128, n0 = blockIdx.x * 128;
    GEMM_BODY(__shared__ float rowss[128][2];)

    // ---- clip ----
#pragma unroll
    for (int mi = 0; mi < 4; ++mi)
#pragma unroll
        for (int ni = 0; ni < 4; ++ni)
#pragma unroll
            for (int r = 0; r < 4; ++r)
                acc[mi][ni][r] = fminf(fmaxf(acc[mi][ni][r], -8.0f), 8.0f);

    if (n0 >= 2560) {  // V: transpose-store, no norm/rope
#pragma unroll
        for (int mi = 0; mi < 4; ++mi)
#pragma unroll
            for (int ni = 0; ni < 4; ++ni)
#pragma unroll
                for (int r = 0; r < 4; ++r) {
                    int row = m0 + mb + mi * 16 + quad * 4 + r;
                    int n = n0 + nb + ni * 16 + l15;
                    vtb[(size_t)(n - 2560) * 2048 + row] = (bf16)acc[mi][ni][r];
                }
        return;
    }

    __syncthreads();  // done reading staging; safe to reuse smem as xnorm
    bf16 (*xnorm)[128] = (bf16(*)[128])(smem + 16384);  // 32 KB alias

    // ---- per-row sum of squares ----
#pragma unroll
    for (int mi = 0; mi < 4; ++mi)
#pragma unroll
        for (int r = 0; r < 4; ++r) {
            float s = 0.f;
#pragma unroll
            for (int ni = 0; ni < 4; ++ni) s += acc[mi][ni][r] * acc[mi][ni][r];
#pragma unroll
            for (int o = 1; o < 16; o <<= 1) s += __shfl_xor(s, o, 64);
            if (l15 == 0) rowss[mb + mi * 16 + quad * 4 + r][wid >> 1] = s;
        }
    __syncthreads();

    // ---- normalize (fp32), stash for rope pairing ----
    const float* nw = (n0 < 2048) ? qw : kw;
#pragma unroll
    for (int mi = 0; mi < 4; ++mi)
#pragma unroll
        for (int r = 0; r < 4; ++r) {
            int row = mb + mi * 16 + quad * 4 + r;
            float var = (rowss[row][0] + rowss[row][1]) * (1.0f / 128.0f);
            float rinv = rsqrtf(var + 1e-6f);
#pragma unroll
            for (int ni = 0; ni < 4; ++ni) {
                int col = nb + ni * 16 + l15;
                float xn = acc[mi][ni][r] * rinv * nw[col];
                acc[mi][ni][r] = xn;
                xnorm[row][col] = (bf16)xn;
            }
        }
    __syncthreads();

    // ---- RoPE + store ----
    float invf[4];
#pragma unroll
    for (int ni = 0; ni < 4; ++ni) {
        int fi = (nb + ni * 16 + l15) & 63;
        invf[ni] = __expf((float)fi * (-13.122363377404328f / 64.0f));
    }
    bool lowhalf = (nb == 0);  // wave-uniform
#pragma unroll
    for (int mi = 0; mi < 4; ++mi)
#pragma unroll
        for (int r = 0; r < 4; ++r) {
            int row = mb + mi * 16 + quad * 4 + r;
            float pos = (float)(m0 + row);
#pragma unroll
            for (int ni = 0; ni < 4; ++ni) {
                int col = nb + ni * 16 + l15;
                float ang = pos * invf[ni];
                float c = __cosf(ang), sn = __sinf(ang);
                float part = (float)xnorm[row][col ^ 64];
                float rot = lowhalf ? -part : part;
                float o = acc[mi][ni][r] * c + rot * sn;
                int n = n0 + col;
                int s = m0 + row;
                if (n0 < 2048) qb[(size_t)s * 2048 + n] = (bf16)o;
                else           kb[(size_t)s * 512 + (n - 2048)] = (bf16)o;
            }
        }
}

// ---------- out-proj GEMM: 128x128 tile, BK=64, dbuf (fp32 out) -------------
__global__ __launch_bounds__(256) void gemm_out(
    const bf16* __restrict__ A, const bf16* __restrict__ B,
    float* __restrict__ C) {
    const int K = 2048, N = 2048;
    int m0 = blockIdx.y * 128, n0 = blockIdx.x * 128;
    GEMM_BODY()
#pragma unroll
    for (int mi = 0; mi < 4; ++mi)
#pragma unroll
        for (int ni = 0; ni < 4; ++ni)
#pragma unroll
            for (int r = 0; r < 4; ++r) {
                int m = m0 + mb + mi * 16 + quad * 4 + r;
                int n = n0 + nb + ni * 16 + l15;
                C[(size_t)m * N + n] = acc[mi][ni][r];
            }
}

// -------- flash attention: double-buffered LDS K/V, fixed-m softmax ----------
__global__ __launch_bounds__(256) void attn(
    const bf16* __restrict__ qb, const bf16* __restrict__ kb,
    const bf16* __restrict__ vtb, const float* __restrict__ sinks,
    bf16* __restrict__ attb) {
    __shared__ __align__(16) bf16 sK[2][64 * 128];   // 32 KB, swizzled
    __shared__ __align__(16) bf16 sV[2][128 * 64];   // 32 KB, swizzled
    __shared__ __align__(16) bf16 sP[4][16 * 72];    // 9 KB per-wave P, padded
    int tid = threadIdx.x;
    int lane = tid & 63, wid = tid >> 6;
    int l15 = lane & 15, quad = lane >> 4;
    int h = blockIdx.y, kh = h >> 2;
    int bq0 = blockIdx.x * 64;
    int qw0 = bq0 + wid * 16;
    bf16* myp = sP[wid];

    bf16x8 qf[4];
    const bf16* qrow = qb + (size_t)(qw0 + l15) * 2048 + h * 128 + quad * 8;
#pragma unroll
    for (int kc = 0; kc < 4; ++kc) qf[kc] = load_bf8(qrow + kc * 32);

    floatx4 acc[8];
#pragma unroll
    for (int f = 0; f < 8; ++f) acc[f] = floatx4{0.f, 0.f, 0.f, 0.f};
    float lpart[4] = {0.f, 0.f, 0.f, 0.f};
    int qi_base = qw0 + quad * 4;

    int keyit = wid * 4 + (lane >> 4);
    int gcK = (lane & 15) ^ keyit;
    int dimit = wid * 8 + (lane >> 3);
    int gcV = (lane & 7) ^ ((lane >> 3) & 7);

    int tstart = bq0 - 1024; if (tstart < 0) tstart = 0;
    const bf16* kbase = kb + (size_t)kh * 128;
    const bf16* vbase = vtb + (size_t)kh * 128 * 2048;

#pragma unroll
    for (int r = 0; r < 4; ++r) {
        async16(kbase + (size_t)(tstart + r * 16 + keyit) * 512 + gcK * 8,
                sK[0] + (r * 16 + wid * 4) * 128);
        async16(vbase + (size_t)(r * 32 + dimit) * 2048 + tstart + gcV * 8,
                sV[0] + (r * 32 + wid * 8) * 64);
    }

    int buf = 0;
    for (int t = tstart; t <= bq0; t += 64) {
        __syncthreads();
        if (t + 64 <= bq0) {
#pragma unroll
            for (int r = 0; r < 4; ++r) {
                async16(kbase + (size_t)(t + 64 + r * 16 + keyit) * 512 + gcK * 8,
                        sK[buf ^ 1] + (r * 16 + wid * 4) * 128);
                async16(vbase + (size_t)(r * 32 + dimit) * 2048 + t + 64 + gcV * 8,
                        sV[buf ^ 1] + (r * 32 + wid * 8) * 64);
            }
        }
        bool active = !((t + 63 <= qw0 - WINDOW) || (t > qw0 + 15));
        if (active) {
            floatx4 s[4];
#pragma unroll
            for (int g = 0; g < 4; ++g) s[g] = floatx4{0.f, 0.f, 0.f, 0.f};
#pragma unroll
            for (int g = 0; g < 4; ++g) {
                int key = g * 16 + l15;
#pragma unroll
                for (int kc = 0; kc < 4; ++kc) {
                    int ch = (kc * 4 + quad) ^ l15;
                    bf16x8 b = load_bf8(sK[buf] + key * 128 + ch * 8);
                    s[g] = __builtin_amdgcn_mfma_f32_16x16x32_bf16(qf[kc], b, s[g], 0, 0, 0);
                }
            }
#pragma unroll
            for (int r = 0; r < 4; ++r) {
                int qi = qi_base + r;
                int row = (quad * 4 + r) * 72;
#pragma unroll
                for (int g = 0; g < 4; ++g) {
                    int ki = t + g * 16 + l15;
                    float v = s[g][r] * 0.08838834764831845f;
                    bool ok = (ki <= qi) && (ki > qi - WINDOW);
                    float e = ok ? __expf(v) : 0.0f;
                    lpart[r] += e;
                    myp[row + g * 16 + l15] = (bf16)e;
                }
            }
            bf16x8 pa0 = load_bf8(myp + l15 * 72 + quad * 8);
            bf16x8 pa1 = load_bf8(myp + l15 * 72 + 32 + quad * 8);
#pragma unroll
            for (int f = 0; f < 8; ++f) {
                int dim = f * 16 + l15;
                int ch0 = quad ^ (l15 & 7);
                int ch1 = (4 + quad) ^ (l15 & 7);
                bf16x8 vb0 = load_bf8(sV[buf] + dim * 64 + ch0 * 8);
                bf16x8 vb1 = load_bf8(sV[buf] + dim * 64 + ch1 * 8);
                acc[f] = __builtin_amdgcn_mfma_f32_16x16x32_bf16(pa0, vb0, acc[f], 0, 0, 0);
                acc[f] = __builtin_amdgcn_mfma_f32_16x16x32_bf16(pa1, vb1, acc[f], 0, 0, 0);
            }
        }
        buf ^= 1;
    }

    float sk = __expf(sinks[h]);
#pragma unroll
    for (int r = 0; r < 4; ++r) {
        float rs = lpart[r];
#pragma unroll
        for (int o = 1; o < 16; o <<= 1) rs += __shfl_xor(rs, o, 64);
        float inv = 1.0f / (rs + sk);
        int m = qw0 + quad * 4 + r;
#pragma unroll
        for (int f = 0; f < 8; ++f) {
            attb[(size_t)m * 2048 + h * 128 + f * 16 + l15] = (bf16)(acc[f][r] * inv);
        }
    }
}

extern "C" void kernel_launch(void* const* d_in, const int* in_sizes, int n_in,
                              void* d_out, int out_size, void* d_ws, size_t ws_size,
                              hipStream_t stream) {
    const float* x      = (const float*)d_in[0];
    const float* w_q    = (const float*)d_in[1];
    const float* w_k    = (const float*)d_in[2];
    const float* w_v    = (const float*)d_in[3];
    const float* w_out  = (const float*)d_in[4];
    const float* q_norm = (const float*)d_in[5];
    const float* k_norm = (const float*)d_in[6];
    const float* sinks  = (const float*)d_in[7];

    char* ws = (char*)d_ws;
    const size_t MB = 1u << 20;
    bf16* xb   = (bf16*)(ws + 0 * MB);    // 8 MB
    bf16* wqb  = (bf16*)(ws + 8 * MB);    // 8 MB  (wqb/wkb/wvb contiguous)
    bf16* wkb  = (bf16*)(ws + 16 * MB);   // 2 MB  (forms wcomb [3072][2048])
    bf16* wvb  = (bf16*)(ws + 18 * MB);   // 2 MB
    bf16* wob  = (bf16*)(ws + 20 * MB);   // 8 MB
    bf16* qb   = (bf16*)(ws + 28 * MB);   // 8 MB  (post norm+rope)
    bf16* kb   = (bf16*)(ws + 36 * MB);   // 2 MB
    bf16* vtb  = (bf16*)(ws + 38 * MB);   // 2 MB  (V transposed)
    bf16* attb = (bf16*)(ws + 40 * MB);   // 8 MB
    bf16* wcomb = wqb;                    // rows 0..3071 = [w_q; w_k; w_v]
    float* out = (float*)d_out;

    convert_kernel<<<14336, 256, 0, stream>>>(x, w_q, w_k, w_v, w_out,
                                              xb, wqb, wkb, wvb, wob);
    gemm_qkv_fused<<<dim3(24, 16), 256, 0, stream>>>(xb, wcomb, q_norm, k_norm,
                                                     qb, kb, vtb);
    attn<<<dim3(32, 16), 256, 0, stream>>>(qb, kb, vtb, sinks, attb);
    gemm_out<<<dim3(16, 16), 256, 0, stream>>>(attb, wob, out);
}